// Round 18
// baseline (623.109 us; speedup 1.0000x reference)
//
#include <hip/hip_runtime.h>
#include <stdint.h>

#define BATCH 2
#define SEQ   2048
#define DM    2048
#define NH    16
#define NKV   4
#define DHD   128
#define FFR   5461
#define FFP   5504          // padded to 128 multiple; 86 tiles of 64 cols
#define NTOK  (BATCH*SEQ)   // 4096
#define QKVW  3072          // fused q|k|v row width

typedef float f32x4 __attribute__((ext_vector_type(4)));
typedef short bf8v __attribute__((ext_vector_type(8)));      // 8 bf16 bit-patterns (4 VGPRs)
typedef unsigned short us8 __attribute__((ext_vector_type(8)));

__device__ __forceinline__ unsigned short f2bf(float f) {
  unsigned u = __float_as_uint(f);
  u += 0x7fff + ((u >> 16) & 1);          // round-to-nearest-even
  return (unsigned short)(u >> 16);
}
__device__ __forceinline__ float bf2f(unsigned short b) {
  return __uint_as_float(((unsigned)b) << 16);
}

// async global->LDS, 16B per lane; LDS dest = wave-uniform base + lane*16 (m104)
__device__ __forceinline__ void gload16(const void* g, void* l) {
  __builtin_amdgcn_global_load_lds(
      (const __attribute__((address_space(1))) unsigned int*)(uintptr_t)g,
      (__attribute__((address_space(3))) unsigned int*)(uintptr_t)l,
      16, 0, 0);
}

// ---------- transpose + f32->bf16 convert: S[K][N] -> T[Npad][Kpad], zero-padded.
// Vectorized (G13): one float4 load + one ushort4 store per thread (512B/wave stores).
__global__ __launch_bounds__(256) void k_transpose(const float* __restrict__ S,
    unsigned short* __restrict__ T, int K, int N, int Kpad)
{
  __shared__ float tile[32][33];
  const int n0 = blockIdx.x << 5, k0 = blockIdx.y << 5;
  const int r = threadIdx.x >> 3;        // 0..31
  const int c4 = (threadIdx.x & 7) << 2; // 0,4,...,28
  float4 v = make_float4(0.f, 0.f, 0.f, 0.f);
  if (k0 + r < K) {
    const float* src = S + (long)(k0 + r) * N + n0 + c4;
    if (((N & 3) == 0) && (n0 + c4 + 4 <= N)) v = *(const float4*)src;
    else {
      if (n0 + c4     < N) v.x = src[0];
      if (n0 + c4 + 1 < N) v.y = src[1];
      if (n0 + c4 + 2 < N) v.z = src[2];
      if (n0 + c4 + 3 < N) v.w = src[3];
    }
  }
  tile[r][c4] = v.x; tile[r][c4+1] = v.y; tile[r][c4+2] = v.z; tile[r][c4+3] = v.w;
  __syncthreads();
  ushort4 o;
  o.x = f2bf(tile[c4  ][r]);
  o.y = f2bf(tile[c4+1][r]);
  o.z = f2bf(tile[c4+2][r]);
  o.w = f2bf(tile[c4+3][r]);
  *(ushort4*)(T + (long)(n0 + r) * Kpad + k0 + c4) = o;
}

// ---------- fused gate/up transpose (vectorized): S[K][N] -> wguT row r'(n,m01).
// r' = (n>>6)*128 + ((n&63)>>4)*32 + m01*16 + (n&15)
__global__ __launch_bounds__(256) void k_transpose_fu(const float* __restrict__ S,
    unsigned short* __restrict__ T, int K, int N, int Kpad, int m01)
{
  __shared__ float tile[32][33];
  const int n0 = blockIdx.x << 5, k0 = blockIdx.y << 5;
  const int r = threadIdx.x >> 3;
  const int c4 = (threadIdx.x & 7) << 2;
  float4 v = make_float4(0.f, 0.f, 0.f, 0.f);
  if (k0 + r < K) {
    const float* src = S + (long)(k0 + r) * N + n0 + c4;
    if (((N & 3) == 0) && (n0 + c4 + 4 <= N)) v = *(const float4*)src;
    else {
      if (n0 + c4     < N) v.x = src[0];
      if (n0 + c4 + 1 < N) v.y = src[1];
      if (n0 + c4 + 2 < N) v.z = src[2];
      if (n0 + c4 + 3 < N) v.w = src[3];
    }
  }
  tile[r][c4] = v.x; tile[r][c4+1] = v.y; tile[r][c4+2] = v.z; tile[r][c4+3] = v.w;
  __syncthreads();
  ushort4 o;
  o.x = f2bf(tile[c4  ][r]);
  o.y = f2bf(tile[c4+1][r]);
  o.z = f2bf(tile[c4+2][r]);
  o.w = f2bf(tile[c4+3][r]);
  const int n = n0 + r;
  long rp = (long)(n >> 6)*128 + ((n & 63) >> 4)*32 + m01*16 + (n & 15);
  *(ushort4*)(T + rp * Kpad + k0 + c4) = o;
}

// ---------- V transpose: qkv[b*SEQ+kv][3072] (V at col 2560+hkv*128+d) -> vbT[(b*4+hkv)*128+d][SEQ]
__global__ __launch_bounds__(256) void k_transpose_v(const unsigned short* __restrict__ KV,
    unsigned short* __restrict__ VT)
{
  __shared__ unsigned short tile[32][36];
  const int kv0 = blockIdx.x << 5, d0 = blockIdx.y << 5;
  const int bz = blockIdx.z;            // b*4+hkv
  const int b = bz >> 2, hkv = bz & 3;
  const int flat = threadIdx.x * 4;
  const int r = flat >> 5, c = flat & 31;
  ushort4 v = *(const ushort4*)(KV + ((long)(b*SEQ + kv0 + r))*QKVW + 2560 + hkv*128 + d0 + c);
  tile[r][c] = v.x; tile[r][c+1] = v.y; tile[r][c+2] = v.z; tile[r][c+3] = v.w;
  __syncthreads();
  ushort4 o;
  o.x = tile[c][r]; o.y = tile[c+1][r]; o.z = tile[c+2][r]; o.w = tile[c+3][r];
  *(ushort4*)(VT + ((long)(bz*128 + d0 + r))*SEQ + kv0 + c) = o;
}

// ---------- RMSNorm: fp32 in -> bf16 out (one row per block, 2048 cols)
__global__ __launch_bounds__(256) void k_rmsnorm(const float* __restrict__ X,
    const float* __restrict__ W, unsigned short* __restrict__ H)
{
  __shared__ float red[4];
  const long row = blockIdx.x;
  const float* xr = X + row * DM;
  const int tid = threadIdx.x;
  float4 a0 = ((const float4*)xr)[2*tid];
  float4 a1 = ((const float4*)xr)[2*tid+1];
  float ss = a0.x*a0.x + a0.y*a0.y + a0.z*a0.z + a0.w*a0.w
           + a1.x*a1.x + a1.y*a1.y + a1.z*a1.z + a1.w*a1.w;
#pragma unroll
  for (int m = 32; m >= 1; m >>= 1) ss += __shfl_xor(ss, m, 64);
  if ((tid & 63) == 0) red[tid >> 6] = ss;
  __syncthreads();
  float sc = rsqrtf((red[0]+red[1]+red[2]+red[3]) * (1.0f/DM) + 1e-6f);
  float4 w0 = ((const float4*)W)[2*tid];
  float4 w1 = ((const float4*)W)[2*tid+1];
  us8 o;
  o[0]=f2bf(a0.x*sc*w0.x); o[1]=f2bf(a0.y*sc*w0.y); o[2]=f2bf(a0.z*sc*w0.z); o[3]=f2bf(a0.w*sc*w0.w);
  o[4]=f2bf(a1.x*sc*w1.x); o[5]=f2bf(a1.y*sc*w1.y); o[6]=f2bf(a1.z*sc*w1.z); o[7]=f2bf(a1.w*sc*w1.w);
  *(us8*)(H + row*DM + tid*8) = o;
}

// ---------- RoPE cos/sin table
__global__ void k_rope_table(float* __restrict__ C, float* __restrict__ S)
{
  int i = blockIdx.x * 256 + threadIdx.x;   // SEQ*64 threads
  int pos = i >> 6, d = i & 63;
  double inv = exp(-(double)d * (9.210340371976184 / 64.0)); // 10000^(-d/64)
  double ang = (double)pos * inv;
  C[i] = (float)cos(ang);
  S[i] = (float)sin(ang);
}

// ---------- RoPE apply in place on bf16, row stride `stride`, head block at head0
__global__ __launch_bounds__(256) void k_rope_apply(unsigned short* __restrict__ Q,
    const float* __restrict__ C, const float* __restrict__ S, int nh, int stride, int head0)
{
  long i = (long)blockIdx.x * 256 + threadIdx.x; // BATCH*SEQ*nh*64
  int d = (int)(i & 63);
  long t = i >> 6;
  int hh = (int)(t % nh);
  long bl = t / nh;                 // b*SEQ + pos
  int pos = (int)(bl & (SEQ-1));
  long base = bl * stride + head0 + hh*DHD;
  float c = C[pos*64 + d], s = S[pos*64 + d];
  float x1 = bf2f(Q[base + d]);
  float x2 = bf2f(Q[base + 64 + d]);
  Q[base + d]      = f2bf(x1*c - x2*s);
  Q[base + 64 + d] = f2bf(x2*c + x1*s);
}

// ---------- 128x128 bf16 MFMA GEMM, double-buffered 2-phase, T2 pre-swizzled LDS,
// bijective XCD swizzle + supertiles with runtime N-width `sw`.
// EPI 0: bf16 store; EPI 1: float = Res + acc; EPI 3: fused SwiGLU
template<int EPI>
__global__ __launch_bounds__(256) void k_gemm(const unsigned short* __restrict__ A,
    const unsigned short* __restrict__ BT, void* Cout, const float* __restrict__ Res,
    int K, int sw, int ldc)
{
  __shared__ __align__(16) unsigned short As[2][128*64];
  __shared__ __align__(16) unsigned short Bs[2][128*64];
  const int tid = threadIdx.x;
  const int l = tid & 63, w = tid >> 6;
  const int wr = w >> 1, wc = w & 1;
  const int nM = gridDim.x, nN = gridDim.y;
  const int nwg = nM * nN;
  const int bid = blockIdx.y * gridDim.x + blockIdx.x;
  const int q8 = nwg >> 3, r8 = nwg & 7, xcd = bid & 7, off8 = bid >> 3;
  const int wg = (xcd < r8 ? xcd*(q8+1) : r8*(q8+1) + (xcd - r8)*q8) + off8;
  const int colTiles = nM * sw;
  const int fullCols = nN / sw, rem = nN % sw;
  int sc, inCol, wN;
  if (wg < fullCols * colTiles) { sc = wg / colTiles; inCol = wg % colTiles; wN = sw; }
  else { sc = fullCols; inCol = wg - fullCols * colTiles; wN = rem; }
  const int perSuper = 2 * wN;
  const int sm = inCol / perSuper, t8 = inCol % perSuper;
  const long m0 = (long)(sm*2 + t8 / wN) * 128;
  const long n0 = (long)(sc*sw + t8 % wN) * 128;
  const char* Ab = (const char*)(A + m0 * (long)K);
  const char* Bb = (const char*)(BT + n0 * (long)K);
  f32x4 acc[4][4] = {};
  const long ldab = (long)K * 2;
  const int nk = K >> 6;
  const int srow = w*32 + (l >> 3);
  const int scol = ((l & 7) ^ (srow & 7)) * 16;   // inverse-swizzled SOURCE (rule #21)
  auto STAGE = [&](int buf, int kt) {
    const long kb = (long)kt * 128;
#pragma unroll
    for (int i = 0; i < 4; ++i) {
      gload16(Ab + (long)(srow + i*8)*ldab + kb + scol, &As[buf][(w*32 + i*8)*64]);
      gload16(Bb + (long)(srow + i*8)*ldab + kb + scol, &Bs[buf][(w*32 + i*8)*64]);
    }
  };
  STAGE(0, 0);
  __syncthreads();
  int cur = 0;
  for (int kt = 0; kt < nk; ++kt) {
    if (kt + 1 < nk) STAGE(cur ^ 1, kt + 1);      // prefetch overlaps MFMA below
#pragma unroll
    for (int kk = 0; kk < 2; ++kk) {
      bf8v af[4], bfv[4];
#pragma unroll
      for (int m = 0; m < 4; ++m) {
        int r = wr*64 + m*16 + (l & 15);
        int offb = (kk*64 + (l >> 4)*16) ^ ((r & 7) << 4);
        af[m] = *(const bf8v*)((const char*)&As[cur][0] + r*128 + offb);
      }
#pragma unroll
      for (int n = 0; n < 4; ++n) {
        int cI = wc*64 + n*16 + (l & 15);
        int offb = (kk*64 + (l >> 4)*16) ^ ((cI & 7) << 4);
        bfv[n] = *(const bf8v*)((const char*)&Bs[cur][0] + cI*128 + offb);
      }
#pragma unroll
      for (int m = 0; m < 4; ++m)
#pragma unroll
        for (int n = 0; n < 4; ++n)
          acc[m][n] = __builtin_amdgcn_mfma_f32_16x16x32_bf16(af[m], bfv[n], acc[m][n], 0, 0, 0);
    }
    __syncthreads();
    cur ^= 1;
  }
  if (EPI == 3) {
    // fused SwiGLU epilogue: frag n even = gate, n+1 = up, same output col
#pragma unroll
    for (int m = 0; m < 4; ++m)
#pragma unroll
      for (int n = 0; n < 4; n += 2)
#pragma unroll
        for (int r = 0; r < 4; ++r) {
          long row = m0 + wr*64 + m*16 + (l >> 4)*4 + r;
          long col = (n0 >> 1) + (wc*2 + (n >> 1))*16 + (l & 15);
          float g = acc[m][n][r], u = acc[m][n+1][r];
          float sv = g / (1.f + __expf(-g));
          ((unsigned short*)Cout)[row * (long)ldc + col] = f2bf(sv * u);
        }
    return;
  }
#pragma unroll
  for (int m = 0; m < 4; ++m)
#pragma unroll
    for (int n = 0; n < 4; ++n)
#pragma unroll
      for (int r = 0; r < 4; ++r) {
        long row = m0 + wr*64 + m*16 + (l >> 4)*4 + r;
        long col = n0 + wc*64 + n*16 + (l & 15);
        long idx = row * (long)ldc + col;
        if (EPI == 0) ((unsigned short*)Cout)[idx] = f2bf(acc[m][n][r]);
        else          ((float*)Cout)[idx] = Res[idx] + acc[m][n][r];
      }
}

// ---------- flash-style causal GQA attention, 64-row q-blocks, 4 waves, 256 threads,
// paired (qt, 31-qt). Q-RoPE fused in register load. T13 defer-max (THR=8).
__global__ __launch_bounds__(256) void k_attn(const unsigned short* __restrict__ QKV,
    const unsigned short* __restrict__ VbT, unsigned short* __restrict__ O,
    const float* __restrict__ Ct, const float* __restrict__ St)
{
  __shared__ __align__(16) unsigned short Ks[64*128];   // [kv][d] rows 256B, swizzled
  __shared__ __align__(16) unsigned short Vs[128*64];   // [d][kv] rows 128B, swizzled
  __shared__ __align__(16) unsigned short Pl[4][16][64];
  const int tid = threadIdx.x, l = tid & 63, w = tid >> 6;  // w in [0,4)
  const int b = blockIdx.z, h = blockIdx.y;
  const int hkv = h >> 2;
  const int la = l & 15, q = l >> 4;
  const float scale = 0.08838834764831845f; // 1/sqrt(128)
  const unsigned short* Kbase = QKV + (long)b*SEQ*QKVW + 2048 + hkv*128;
  const unsigned short* Vtb = VbT + ((long)(b*NKV + hkv))*128*SEQ;

  for (int half = 0; half < 2; ++half) {
    const int qt = half ? (31 - (int)blockIdx.x) : (int)blockIdx.x;
    const int q0 = qt << 6;              // 64-row q block
    bf8v qa[4];
    {
      const int pos = q0 + w*16 + la;
      const unsigned short* qp = QKV + ((long)(b*SEQ + pos))*QKVW + h*DHD + q*8;
#pragma unroll
      for (int kk = 0; kk < 4; ++kk) qa[kk] = *(const bf8v*)(qp + kk*32);
      // fused Q-RoPE: cols kk*32+q*8+j; partner = qa[kk^2]
      const float* Cb = Ct + pos*64 + q*8;
      const float* Sb = St + pos*64 + q*8;
      float a0[8], a1[8], a2[8], a3[8];
#pragma unroll
      for (int j = 0; j < 8; ++j) {
        a0[j] = bf2f((unsigned short)qa[0][j]);
        a1[j] = bf2f((unsigned short)qa[1][j]);
        a2[j] = bf2f((unsigned short)qa[2][j]);
        a3[j] = bf2f((unsigned short)qa[3][j]);
      }
#pragma unroll
      for (int j = 0; j < 8; ++j) {
        float c0 = Cb[j], s0 = Sb[j], c1 = Cb[32 + j], s1 = Sb[32 + j];
        qa[0][j] = (short)f2bf(a0[j]*c0 - a2[j]*s0);
        qa[1][j] = (short)f2bf(a1[j]*c1 - a3[j]*s1);
        qa[2][j] = (short)f2bf(a2[j]*c0 + a0[j]*s0);
        qa[3][j] = (short)f2bf(a3[j]*c1 + a1[j]*s1);
      }
    }
    float m_[4], s_[4];
    f32x4 o_[8] = {};
#pragma unroll
    for (int r = 0; r < 4; ++r) { m_[r] = -1e30f; s_[r] = 0.f; }
    const int T = qt + 1;

    for (int t = 0; t < T; ++t) {
      const int kv0 = t << 6;
      // ---- stage K 64x128 (256B rows) + V^T 128x64 (128B rows), single buffer
#pragma unroll
      for (int i = 0; i < 4; ++i) {
        int r = w*16 + i*4 + (l >> 4);
        int blk = (l & 15) ^ (r & 7);
        gload16(Kbase + ((long)(kv0 + r))*QKVW + blk*8, Ks + (w*16 + i*4)*128);
      }
#pragma unroll
      for (int i = 0; i < 4; ++i) {
        int r = w*32 + i*8 + (l >> 3);
        int blk = (l & 7) ^ (r & 7);
        gload16(Vtb + (long)r*SEQ + kv0 + blk*8, Vs + (w*32 + i*8)*64);
      }
      __syncthreads();                   // loads landed (vmcnt+lgkm drained)

      f32x4 sc4[4] = {};
      __builtin_amdgcn_s_setprio(1);
#pragma unroll
      for (int n = 0; n < 4; ++n) {
        int row = n*16 + la;
        const char* kr = (const char*)Ks + row*256;
#pragma unroll
        for (int kk = 0; kk < 4; ++kk) {
          int off = (kk*64 + q*16) ^ ((row & 7) << 4);
          bf8v kf = *(const bf8v*)(kr + off);
          sc4[n] = __builtin_amdgcn_mfma_f32_16x16x32_bf16(qa[kk], kf, sc4[n], 0, 0, 0);
        }
      }
      __builtin_amdgcn_s_setprio(0);
      float p[4][4];
      float rmax[4] = {-3e30f, -3e30f, -3e30f, -3e30f};
#pragma unroll
      for (int n = 0; n < 4; ++n) {
        int kv = kv0 + n*16 + la;
#pragma unroll
        for (int r = 0; r < 4; ++r) {
          int qr = q0 + w*16 + q*4 + r;
          float v = sc4[n][r] * scale;
          if (kv > qr) v = -1e30f;
          p[n][r] = v;
          rmax[r] = fmaxf(rmax[r], v);
        }
      }
#pragma unroll
      for (int r = 0; r < 4; ++r) {
        rmax[r] = fmaxf(rmax[r], __shfl_xor(rmax[r], 1, 64));
        rmax[r] = fmaxf(rmax[r], __shfl_xor(rmax[r], 2, 64));
        rmax[r] = fmaxf(rmax[r], __shfl_xor(rmax[r], 4, 64));
        rmax[r] = fmaxf(rmax[r], __shfl_xor(rmax[r], 8, 64));
      }
      // T13 defer-max: only rescale when max grew by more than THR=8
      bool grow = false;
#pragma unroll
      for (int r = 0; r < 4; ++r) grow = grow || (rmax[r] > m_[r] + 8.f);
      if (__any(grow)) {
#pragma unroll
        for (int r = 0; r < 4; ++r) {
          float mn = fmaxf(m_[r], rmax[r]);
          float a = __expf(m_[r] - mn);
          m_[r] = mn;
          s_[r] *= a;
          o_[0][r] *= a; o_[1][r] *= a; o_[2][r] *= a; o_[3][r] *= a;
          o_[4][r] *= a; o_[5][r] *= a; o_[6][r] *= a; o_[7][r] *= a;
        }
      }
      float ps[4] = {0.f, 0.f, 0.f, 0.f};
#pragma unroll
      for (int n = 0; n < 4; ++n)
#pragma unroll
        for (int r = 0; r < 4; ++r) {
          float e = __expf(p[n][r] - m_[r]);
          p[n][r] = e;
          ps[r] += e;
        }
#pragma unroll
      for (int r = 0; r < 4; ++r) {
        ps[r] += __shfl_xor(ps[r], 1, 64);
        ps[r] += __shfl_xor(ps[r], 2, 64);
        ps[r] += __shfl_xor(ps[r], 4, 64);
        ps[r] += __shfl_xor(ps[r], 8, 64);
        s_[r] += ps[r];
      }
#pragma unroll
      for (int n = 0; n < 4; ++n)
#pragma unroll
        for (int r = 0; r < 4; ++r)
          Pl[w][q*4 + r][n*16 + la] = f2bf(p[n][r]);
      __builtin_amdgcn_s_setprio(1);
#pragma unroll
      for (int kk2 = 0; kk2 < 2; ++kk2) {
        bf8v pa = *(const bf8v*)&Pl[w][la][kk2*32 + q*8];
#pragma unroll
        for (int g = 0; g < 8; ++g) {
          int d = g*16 + la;
          int off = (kk2*64 + q*16) ^ ((d & 7) << 4);
          bf8v vf = *(const bf8v*)((const char*)Vs + d*128 + off);
          o_[g] = __builtin_amdgcn_mfma_f32_16x16x32_bf16(pa, vf, o_[g], 0, 0, 0);
        }
      }
      __builtin_amdgcn_s_setprio(0);
      __syncthreads();                   // all reads done before next-tile overwrite
    }
#pragma unroll
    for (int g = 0; g < 8; ++g)
#pragma unroll
      for (int r = 0; r < 4; ++r) {
        long row = (long)b*SEQ + q0 + w*16 + q*4 + r;
        O[row*DM + h*DHD + g*16 + la] = f2bf(o_[g][r] / s_[r]);
      }
  }
}

extern "C" void kernel_launch(void* const* d_in, const int* in_sizes, int n_in,
                              void* d_out, int out_size, void* d_ws, size_t ws_size,
                              hipStream_t stream)
{
  const float* x   = (const float*)d_in[0];
  const float* wn1 = (const float*)d_in[1];
  const float* wq  = (const float*)d_in[2];
  const float* wk  = (const float*)d_in[3];
  const float* wv  = (const float*)d_in[4];
  const float* wo  = (const float*)d_in[5];
  const float* wn2 = (const float*)d_in[6];
  const float* wg  = (const float*)d_in[7];
  const float* wu  = (const float*)d_in[8];
  const float* wd  = (const float*)d_in[9];
  float* out = (float*)d_out;

  char* p = (char*)d_ws;
  auto alloc = [&](size_t bytes) { char* r = p; p += (bytes + 255) & ~(size_t)255; return r; };
  unsigned short* wqkvT = (unsigned short*)alloc((size_t)QKVW*2048*2);
  unsigned short* woT   = (unsigned short*)alloc((size_t)2048*2048*2);
  unsigned short* wguT  = (unsigned short*)alloc((size_t)2*FFP*2048*2);   // interleaved gate/up
  unsigned short* wdT   = (unsigned short*)alloc((size_t)2048*FFP*2);
  unsigned short* hb    = (unsigned short*)alloc((size_t)NTOK*2048*2);
  unsigned short* pr    = (unsigned short*)alloc((size_t)NTOK*FFP*2);
  unsigned short* qkv   = (unsigned short*)alloc((size_t)NTOK*QKVW*2);
  unsigned short* vbT   = (unsigned short*)alloc((size_t)BATCH*NKV*128*SEQ*2);
  unsigned short* ao    = (unsigned short*)alloc((size_t)NTOK*2048*2);
  float* ctab = (float*)alloc((size_t)SEQ*64*4);
  float* stab = (float*)alloc((size_t)SEQ*64*4);

  dim3 blk(256);
  k_transpose<<<dim3(2048/32, 2048/32), blk, 0, stream>>>(wq, wqkvT, 2048, 2048, 2048);
  k_transpose<<<dim3(512/32,  2048/32), blk, 0, stream>>>(wk, wqkvT + (size_t)2048*2048, 2048, 512, 2048);
  k_transpose<<<dim3(512/32,  2048/32), blk, 0, stream>>>(wv, wqkvT + (size_t)2560*2048, 2048, 512, 2048);
  k_transpose<<<dim3(2048/32, 2048/32), blk, 0, stream>>>(wo, woT, 2048, 2048, 2048);
  k_transpose_fu<<<dim3(FFP/32, 2048/32), blk, 0, stream>>>(wg, wguT, 2048, FFR, 2048, 0);
  k_transpose_fu<<<dim3(FFP/32, 2048/32), blk, 0, stream>>>(wu, wguT, 2048, FFR, 2048, 1);
  k_transpose<<<dim3(2048/32, FFP/32),  blk, 0, stream>>>(wd, wdT, FFR, 2048, FFP);

  k_rope_table<<<dim3(SEQ*64/256), blk, 0, stream>>>(ctab, stab);
  k_rmsnorm<<<dim3(NTOK), blk, 0, stream>>>(x, wn1, hb);

  k_gemm<0><<<dim3(32, QKVW/128), blk, 0, stream>>>(hb, wqkvT, qkv, nullptr, 2048, 4, QKVW);

  // K-RoPE in memory (small); Q-RoPE is fused into k_attn's register load
  k_rope_apply<<<dim3(NTOK*NKV*64/256), blk, 0, stream>>>(qkv, ctab, stab, NKV, QKVW, 2048);

  k_transpose_v<<<dim3(SEQ/32, 128/32, BATCH*NKV), blk, 0, stream>>>(qkv, vbT);

  k_attn<<<dim3(16, NH, BATCH), blk, 0, stream>>>(qkv, vbT, ao, ctab, stab);

  k_gemm<1><<<dim3(32, 16), blk, 0, stream>>>(ao, woT, (void*)out, x, 2048, 4, 2048);
  k_rmsnorm<<<dim3(NTOK), blk, 0, stream>>>(out, wn2, hb);
  // fused gate+up: B has 2*FFP rows (86 tiles x 128), output FFP cols of silu(g)*u
  k_gemm<3><<<dim3(32, 2*FFP/128), blk, 0, stream>>>(hb, wguT, pr, nullptr, 2048, 4, FFP);
  // down-proj K=5504: sw=2 keeps B-chunk (2.8 MB) L2-resident
  k_gemm<1><<<dim3(32, 16), blk, 0, stream>>>(pr, wdT, (void*)out, out, FFP, 2, 2048);
}

// Round 19
// 614.809 us; speedup vs baseline: 1.0135x; 1.0135x over previous
//
#include <hip/hip_runtime.h>
#include <stdint.h>

#define BATCH 2
#define SEQ   2048
#define DM    2048
#define NH    16
#define NKV   4
#define DHD   128
#define FFR   5461
#define FFP   5504          // padded to 128 multiple; 86 tiles of 64 cols
#define NTOK  (BATCH*SEQ)   // 4096
#define QKVW  3072          // fused q|k|v row width

typedef float f32x4 __attribute__((ext_vector_type(4)));
typedef short bf8v __attribute__((ext_vector_type(8)));      // 8 bf16 bit-patterns (4 VGPRs)
typedef unsigned short us8 __attribute__((ext_vector_type(8)));

__device__ __forceinline__ unsigned short f2bf(float f) {
  unsigned u = __float_as_uint(f);
  u += 0x7fff + ((u >> 16) & 1);          // round-to-nearest-even
  return (unsigned short)(u >> 16);
}
__device__ __forceinline__ float bf2f(unsigned short b) {
  return __uint_as_float(((unsigned)b) << 16);
}

// async global->LDS, 16B per lane; LDS dest = wave-uniform base + lane*16 (m104)
__device__ __forceinline__ void gload16(const void* g, void* l) {
  __builtin_amdgcn_global_load_lds(
      (const __attribute__((address_space(1))) unsigned int*)(uintptr_t)g,
      (__attribute__((address_space(3))) unsigned int*)(uintptr_t)l,
      16, 0, 0);
}

// ---------- transpose + f32->bf16 convert: S[K][N] -> T[Npad][Kpad], zero-padded.
// Vectorized (G13): one float4 load + one ushort4 store per thread (512B/wave stores).
__global__ __launch_bounds__(256) void k_transpose(const float* __restrict__ S,
    unsigned short* __restrict__ T, int K, int N, int Kpad)
{
  __shared__ float tile[32][33];
  const int n0 = blockIdx.x << 5, k0 = blockIdx.y << 5;
  const int r = threadIdx.x >> 3;        // 0..31
  const int c4 = (threadIdx.x & 7) << 2; // 0,4,...,28
  float4 v = make_float4(0.f, 0.f, 0.f, 0.f);
  if (k0 + r < K) {
    const float* src = S + (long)(k0 + r) * N + n0 + c4;
    if (((N & 3) == 0) && (n0 + c4 + 4 <= N)) v = *(const float4*)src;
    else {
      if (n0 + c4     < N) v.x = src[0];
      if (n0 + c4 + 1 < N) v.y = src[1];
      if (n0 + c4 + 2 < N) v.z = src[2];
      if (n0 + c4 + 3 < N) v.w = src[3];
    }
  }
  tile[r][c4] = v.x; tile[r][c4+1] = v.y; tile[r][c4+2] = v.z; tile[r][c4+3] = v.w;
  __syncthreads();
  ushort4 o;
  o.x = f2bf(tile[c4  ][r]);
  o.y = f2bf(tile[c4+1][r]);
  o.z = f2bf(tile[c4+2][r]);
  o.w = f2bf(tile[c4+3][r]);
  *(ushort4*)(T + (long)(n0 + r) * Kpad + k0 + c4) = o;
}

// ---------- fused gate/up transpose (vectorized): S[K][N] -> wguT row r'(n,m01).
// r' = (n>>6)*128 + ((n&63)>>4)*32 + m01*16 + (n&15)
__global__ __launch_bounds__(256) void k_transpose_fu(const float* __restrict__ S,
    unsigned short* __restrict__ T, int K, int N, int Kpad, int m01)
{
  __shared__ float tile[32][33];
  const int n0 = blockIdx.x << 5, k0 = blockIdx.y << 5;
  const int r = threadIdx.x >> 3;
  const int c4 = (threadIdx.x & 7) << 2;
  float4 v = make_float4(0.f, 0.f, 0.f, 0.f);
  if (k0 + r < K) {
    const float* src = S + (long)(k0 + r) * N + n0 + c4;
    if (((N & 3) == 0) && (n0 + c4 + 4 <= N)) v = *(const float4*)src;
    else {
      if (n0 + c4     < N) v.x = src[0];
      if (n0 + c4 + 1 < N) v.y = src[1];
      if (n0 + c4 + 2 < N) v.z = src[2];
      if (n0 + c4 + 3 < N) v.w = src[3];
    }
  }
  tile[r][c4] = v.x; tile[r][c4+1] = v.y; tile[r][c4+2] = v.z; tile[r][c4+3] = v.w;
  __syncthreads();
  ushort4 o;
  o.x = f2bf(tile[c4  ][r]);
  o.y = f2bf(tile[c4+1][r]);
  o.z = f2bf(tile[c4+2][r]);
  o.w = f2bf(tile[c4+3][r]);
  const int n = n0 + r;
  long rp = (long)(n >> 6)*128 + ((n & 63) >> 4)*32 + m01*16 + (n & 15);
  *(ushort4*)(T + rp * Kpad + k0 + c4) = o;
}

// ---------- V transpose: qkv[b*SEQ+kv][3072] (V at col 2560+hkv*128+d) -> vbT[(b*4+hkv)*128+d][SEQ]
__global__ __launch_bounds__(256) void k_transpose_v(const unsigned short* __restrict__ KV,
    unsigned short* __restrict__ VT)
{
  __shared__ unsigned short tile[32][36];
  const int kv0 = blockIdx.x << 5, d0 = blockIdx.y << 5;
  const int bz = blockIdx.z;            // b*4+hkv
  const int b = bz >> 2, hkv = bz & 3;
  const int flat = threadIdx.x * 4;
  const int r = flat >> 5, c = flat & 31;
  ushort4 v = *(const ushort4*)(KV + ((long)(b*SEQ + kv0 + r))*QKVW + 2560 + hkv*128 + d0 + c);
  tile[r][c] = v.x; tile[r][c+1] = v.y; tile[r][c+2] = v.z; tile[r][c+3] = v.w;
  __syncthreads();
  ushort4 o;
  o.x = tile[c][r]; o.y = tile[c+1][r]; o.z = tile[c+2][r]; o.w = tile[c+3][r];
  *(ushort4*)(VT + ((long)(bz*128 + d0 + r))*SEQ + kv0 + c) = o;
}

// ---------- RMSNorm: fp32 in -> bf16 out (one row per block, 2048 cols)
__global__ __launch_bounds__(256) void k_rmsnorm(const float* __restrict__ X,
    const float* __restrict__ W, unsigned short* __restrict__ H)
{
  __shared__ float red[4];
  const long row = blockIdx.x;
  const float* xr = X + row * DM;
  const int tid = threadIdx.x;
  float4 a0 = ((const float4*)xr)[2*tid];
  float4 a1 = ((const float4*)xr)[2*tid+1];
  float ss = a0.x*a0.x + a0.y*a0.y + a0.z*a0.z + a0.w*a0.w
           + a1.x*a1.x + a1.y*a1.y + a1.z*a1.z + a1.w*a1.w;
#pragma unroll
  for (int m = 32; m >= 1; m >>= 1) ss += __shfl_xor(ss, m, 64);
  if ((tid & 63) == 0) red[tid >> 6] = ss;
  __syncthreads();
  float sc = rsqrtf((red[0]+red[1]+red[2]+red[3]) * (1.0f/DM) + 1e-6f);
  float4 w0 = ((const float4*)W)[2*tid];
  float4 w1 = ((const float4*)W)[2*tid+1];
  us8 o;
  o[0]=f2bf(a0.x*sc*w0.x); o[1]=f2bf(a0.y*sc*w0.y); o[2]=f2bf(a0.z*sc*w0.z); o[3]=f2bf(a0.w*sc*w0.w);
  o[4]=f2bf(a1.x*sc*w1.x); o[5]=f2bf(a1.y*sc*w1.y); o[6]=f2bf(a1.z*sc*w1.z); o[7]=f2bf(a1.w*sc*w1.w);
  *(us8*)(H + row*DM + tid*8) = o;
}

// ---------- RoPE cos/sin table
__global__ void k_rope_table(float* __restrict__ C, float* __restrict__ S)
{
  int i = blockIdx.x * 256 + threadIdx.x;   // SEQ*64 threads
  int pos = i >> 6, d = i & 63;
  double inv = exp(-(double)d * (9.210340371976184 / 64.0)); // 10000^(-d/64)
  double ang = (double)pos * inv;
  C[i] = (float)cos(ang);
  S[i] = (float)sin(ang);
}

// ---------- RoPE apply in place on bf16, row stride `stride`, head block at head0
__global__ __launch_bounds__(256) void k_rope_apply(unsigned short* __restrict__ Q,
    const float* __restrict__ C, const float* __restrict__ S, int nh, int stride, int head0)
{
  long i = (long)blockIdx.x * 256 + threadIdx.x; // BATCH*SEQ*nh*64
  int d = (int)(i & 63);
  long t = i >> 6;
  int hh = (int)(t % nh);
  long bl = t / nh;                 // b*SEQ + pos
  int pos = (int)(bl & (SEQ-1));
  long base = bl * stride + head0 + hh*DHD;
  float c = C[pos*64 + d], s = S[pos*64 + d];
  float x1 = bf2f(Q[base + d]);
  float x2 = bf2f(Q[base + 64 + d]);
  Q[base + d]      = f2bf(x1*c - x2*s);
  Q[base + 64 + d] = f2bf(x2*c + x1*s);
}

// ---------- 128x128 bf16 MFMA GEMM, double-buffered 2-phase, T2 pre-swizzled LDS,
// bijective XCD swizzle + supertiles with runtime N-width `sw`.
// EPI 0: bf16 store; EPI 1: float = Res + acc; EPI 3: fused SwiGLU
template<int EPI>
__global__ __launch_bounds__(256) void k_gemm(const unsigned short* __restrict__ A,
    const unsigned short* __restrict__ BT, void* Cout, const float* __restrict__ Res,
    int K, int sw, int ldc)
{
  __shared__ __align__(16) unsigned short As[2][128*64];
  __shared__ __align__(16) unsigned short Bs[2][128*64];
  const int tid = threadIdx.x;
  const int l = tid & 63, w = tid >> 6;
  const int wr = w >> 1, wc = w & 1;
  const int nM = gridDim.x, nN = gridDim.y;
  const int nwg = nM * nN;
  const int bid = blockIdx.y * gridDim.x + blockIdx.x;
  if ((bid >> 8) & 1) {                         // stagger co-resident pair (round-17 best cfg)
    asm volatile("s_sleep 15\ns_sleep 15\ns_sleep 15\ns_sleep 15" ::: "memory");
  }
  const int q8 = nwg >> 3, r8 = nwg & 7, xcd = bid & 7, off8 = bid >> 3;
  const int wg = (xcd < r8 ? xcd*(q8+1) : r8*(q8+1) + (xcd - r8)*q8) + off8;
  const int colTiles = nM * sw;
  const int fullCols = nN / sw, rem = nN % sw;
  int sc, inCol, wN;
  if (wg < fullCols * colTiles) { sc = wg / colTiles; inCol = wg % colTiles; wN = sw; }
  else { sc = fullCols; inCol = wg - fullCols * colTiles; wN = rem; }
  const int perSuper = 2 * wN;
  const int sm = inCol / perSuper, t8 = inCol % perSuper;
  const long m0 = (long)(sm*2 + t8 / wN) * 128;
  const long n0 = (long)(sc*sw + t8 % wN) * 128;
  const char* Ab = (const char*)(A + m0 * (long)K);
  const char* Bb = (const char*)(BT + n0 * (long)K);
  f32x4 acc[4][4] = {};
  const long ldab = (long)K * 2;
  const int nk = K >> 6;
  const int srow = w*32 + (l >> 3);
  const int scol = ((l & 7) ^ (srow & 7)) * 16;   // inverse-swizzled SOURCE (rule #21)
  auto STAGE = [&](int buf, int kt) {
    const long kb = (long)kt * 128;
#pragma unroll
    for (int i = 0; i < 4; ++i) {
      gload16(Ab + (long)(srow + i*8)*ldab + kb + scol, &As[buf][(w*32 + i*8)*64]);
      gload16(Bb + (long)(srow + i*8)*ldab + kb + scol, &Bs[buf][(w*32 + i*8)*64]);
    }
  };
  STAGE(0, 0);
  __syncthreads();
  int cur = 0;
  for (int kt = 0; kt < nk; ++kt) {
    if (kt + 1 < nk) STAGE(cur ^ 1, kt + 1);      // prefetch overlaps MFMA below
#pragma unroll
    for (int kk = 0; kk < 2; ++kk) {
      bf8v af[4], bfv[4];
#pragma unroll
      for (int m = 0; m < 4; ++m) {
        int r = wr*64 + m*16 + (l & 15);
        int offb = (kk*64 + (l >> 4)*16) ^ ((r & 7) << 4);
        af[m] = *(const bf8v*)((const char*)&As[cur][0] + r*128 + offb);
      }
#pragma unroll
      for (int n = 0; n < 4; ++n) {
        int cI = wc*64 + n*16 + (l & 15);
        int offb = (kk*64 + (l >> 4)*16) ^ ((cI & 7) << 4);
        bfv[n] = *(const bf8v*)((const char*)&Bs[cur][0] + cI*128 + offb);
      }
#pragma unroll
      for (int m = 0; m < 4; ++m)
#pragma unroll
        for (int n = 0; n < 4; ++n)
          acc[m][n] = __builtin_amdgcn_mfma_f32_16x16x32_bf16(af[m], bfv[n], acc[m][n], 0, 0, 0);
    }
    __syncthreads();
    cur ^= 1;
  }
  if (EPI == 3) {
    // fused SwiGLU epilogue: frag n even = gate, n+1 = up, same output col
#pragma unroll
    for (int m = 0; m < 4; ++m)
#pragma unroll
      for (int n = 0; n < 4; n += 2)
#pragma unroll
        for (int r = 0; r < 4; ++r) {
          long row = m0 + wr*64 + m*16 + (l >> 4)*4 + r;
          long col = (n0 >> 1) + (wc*2 + (n >> 1))*16 + (l & 15);
          float g = acc[m][n][r], u = acc[m][n+1][r];
          float sv = g / (1.f + __expf(-g));
          ((unsigned short*)Cout)[row * (long)ldc + col] = f2bf(sv * u);
        }
    return;
  }
#pragma unroll
  for (int m = 0; m < 4; ++m)
#pragma unroll
    for (int n = 0; n < 4; ++n)
#pragma unroll
      for (int r = 0; r < 4; ++r) {
        long row = m0 + wr*64 + m*16 + (l >> 4)*4 + r;
        long col = n0 + wc*64 + n*16 + (l & 15);
        long idx = row * (long)ldc + col;
        if (EPI == 0) ((unsigned short*)Cout)[idx] = f2bf(acc[m][n][r]);
        else          ((float*)Cout)[idx] = Res[idx] + acc[m][n][r];
      }
}

// ---------- flash-style causal GQA attention, 64-row q-blocks, 4 waves, 256 threads,
// paired (qt, 31-qt). Q-RoPE fused in register load. T13 defer-max (THR=8).
__global__ __launch_bounds__(256) void k_attn(const unsigned short* __restrict__ QKV,
    const unsigned short* __restrict__ VbT, unsigned short* __restrict__ O,
    const float* __restrict__ Ct, const float* __restrict__ St)
{
  __shared__ __align__(16) unsigned short Ks[64*128];   // [kv][d] rows 256B, swizzled
  __shared__ __align__(16) unsigned short Vs[128*64];   // [d][kv] rows 128B, swizzled
  __shared__ __align__(16) unsigned short Pl[4][16][64];
  const int tid = threadIdx.x, l = tid & 63, w = tid >> 6;  // w in [0,4)
  const int b = blockIdx.z, h = blockIdx.y;
  const int hkv = h >> 2;
  const int la = l & 15, q = l >> 4;
  const int lin = (int)(blockIdx.x + (blockIdx.y << 4) + (blockIdx.z << 8));
  if ((lin >> 8) & 1) {
    asm volatile("s_sleep 15\ns_sleep 15\ns_sleep 15\ns_sleep 15" ::: "memory");
  }
  const float scale = 0.08838834764831845f; // 1/sqrt(128)
  const unsigned short* Kbase = QKV + (long)b*SEQ*QKVW + 2048 + hkv*128;
  const unsigned short* Vtb = VbT + ((long)(b*NKV + hkv))*128*SEQ;

  for (int half = 0; half < 2; ++half) {
    const int qt = half ? (31 - (int)blockIdx.x) : (int)blockIdx.x;
    const int q0 = qt << 6;              // 64-row q block
    bf8v qa[4];
    {
      const int pos = q0 + w*16 + la;
      const unsigned short* qp = QKV + ((long)(b*SEQ + pos))*QKVW + h*DHD + q*8;
#pragma unroll
      for (int kk = 0; kk < 4; ++kk) qa[kk] = *(const bf8v*)(qp + kk*32);
      // fused Q-RoPE: cols kk*32+q*8+j; partner = qa[kk^2]
      const float* Cb = Ct + pos*64 + q*8;
      const float* Sb = St + pos*64 + q*8;
      float a0[8], a1[8], a2[8], a3[8];
#pragma unroll
      for (int j = 0; j < 8; ++j) {
        a0[j] = bf2f((unsigned short)qa[0][j]);
        a1[j] = bf2f((unsigned short)qa[1][j]);
        a2[j] = bf2f((unsigned short)qa[2][j]);
        a3[j] = bf2f((unsigned short)qa[3][j]);
      }
#pragma unroll
      for (int j = 0; j < 8; ++j) {
        float c0 = Cb[j], s0 = Sb[j], c1 = Cb[32 + j], s1 = Sb[32 + j];
        qa[0][j] = (short)f2bf(a0[j]*c0 - a2[j]*s0);
        qa[1][j] = (short)f2bf(a1[j]*c1 - a3[j]*s1);
        qa[2][j] = (short)f2bf(a2[j]*c0 + a0[j]*s0);
        qa[3][j] = (short)f2bf(a3[j]*c1 + a1[j]*s1);
      }
    }
    float m_[4], s_[4];
    f32x4 o_[8] = {};
#pragma unroll
    for (int r = 0; r < 4; ++r) { m_[r] = -1e30f; s_[r] = 0.f; }
    const int T = qt + 1;

    for (int t = 0; t < T; ++t) {
      const int kv0 = t << 6;
      // ---- stage K 64x128 (256B rows) + V^T 128x64 (128B rows), single buffer
#pragma unroll
      for (int i = 0; i < 4; ++i) {
        int r = w*16 + i*4 + (l >> 4);
        int blk = (l & 15) ^ (r & 7);
        gload16(Kbase + ((long)(kv0 + r))*QKVW + blk*8, Ks + (w*16 + i*4)*128);
      }
#pragma unroll
      for (int i = 0; i < 4; ++i) {
        int r = w*32 + i*8 + (l >> 3);
        int blk = (l & 7) ^ (r & 7);
        gload16(Vtb + (long)r*SEQ + kv0 + blk*8, Vs + (w*32 + i*8)*64);
      }
      __syncthreads();                   // loads landed (vmcnt+lgkm drained)

      f32x4 sc4[4] = {};
      __builtin_amdgcn_s_setprio(1);
#pragma unroll
      for (int n = 0; n < 4; ++n) {
        int row = n*16 + la;
        const char* kr = (const char*)Ks + row*256;
#pragma unroll
        for (int kk = 0; kk < 4; ++kk) {
          int off = (kk*64 + q*16) ^ ((row & 7) << 4);
          bf8v kf = *(const bf8v*)(kr + off);
          sc4[n] = __builtin_amdgcn_mfma_f32_16x16x32_bf16(qa[kk], kf, sc4[n], 0, 0, 0);
        }
      }
      __builtin_amdgcn_s_setprio(0);
      float p[4][4];
      float rmax[4] = {-3e30f, -3e30f, -3e30f, -3e30f};
#pragma unroll
      for (int n = 0; n < 4; ++n) {
        int kv = kv0 + n*16 + la;
#pragma unroll
        for (int r = 0; r < 4; ++r) {
          int qr = q0 + w*16 + q*4 + r;
          float v = sc4[n][r] * scale;
          if (kv > qr) v = -1e30f;
          p[n][r] = v;
          rmax[r] = fmaxf(rmax[r], v);
        }
      }
#pragma unroll
      for (int r = 0; r < 4; ++r) {
        rmax[r] = fmaxf(rmax[r], __shfl_xor(rmax[r], 1, 64));
        rmax[r] = fmaxf(rmax[r], __shfl_xor(rmax[r], 2, 64));
        rmax[r] = fmaxf(rmax[r], __shfl_xor(rmax[r], 4, 64));
        rmax[r] = fmaxf(rmax[r], __shfl_xor(rmax[r], 8, 64));
      }
      // T13 defer-max: only rescale when max grew by more than THR=8
      bool grow = false;
#pragma unroll
      for (int r = 0; r < 4; ++r) grow = grow || (rmax[r] > m_[r] + 8.f);
      if (__any(grow)) {
#pragma unroll
        for (int r = 0; r < 4; ++r) {
          float mn = fmaxf(m_[r], rmax[r]);
          float a = __expf(m_[r] - mn);
          m_[r] = mn;
          s_[r] *= a;
          o_[0][r] *= a; o_[1][r] *= a; o_[2][r] *= a; o_[3][r] *= a;
          o_[4][r] *= a; o_[5][r] *= a; o_[6][r] *= a; o_[7][r] *= a;
        }
      }
      float ps[4] = {0.f, 0.f, 0.f, 0.f};
#pragma unroll
      for (int n = 0; n < 4; ++n)
#pragma unroll
        for (int r = 0; r < 4; ++r) {
          float e = __expf(p[n][r] - m_[r]);
          p[n][r] = e;
          ps[r] += e;
        }
#pragma unroll
      for (int r = 0; r < 4; ++r) {
        ps[r] += __shfl_xor(ps[r], 1, 64);
        ps[r] += __shfl_xor(ps[r], 2, 64);
        ps[r] += __shfl_xor(ps[r], 4, 64);
        ps[r] += __shfl_xor(ps[r], 8, 64);
        s_[r] += ps[r];
      }
#pragma unroll
      for (int n = 0; n < 4; ++n)
#pragma unroll
        for (int r = 0; r < 4; ++r)
          Pl[w][q*4 + r][n*16 + la] = f2bf(p[n][r]);
      __builtin_amdgcn_s_setprio(1);
#pragma unroll
      for (int kk2 = 0; kk2 < 2; ++kk2) {
        bf8v pa = *(const bf8v*)&Pl[w][la][kk2*32 + q*8];
#pragma unroll
        for (int g = 0; g < 8; ++g) {
          int d = g*16 + la;
          int off = (kk2*64 + q*16) ^ ((d & 7) << 4);
          bf8v vf = *(const bf8v*)((const char*)Vs + d*128 + off);
          o_[g] = __builtin_amdgcn_mfma_f32_16x16x32_bf16(pa, vf, o_[g], 0, 0, 0);
        }
      }
      __builtin_amdgcn_s_setprio(0);
      __syncthreads();                   // all reads done before next-tile overwrite
    }
#pragma unroll
    for (int g = 0; g < 8; ++g)
#pragma unroll
      for (int r = 0; r < 4; ++r) {
        long row = (long)b*SEQ + q0 + w*16 + q*4 + r;
        O[row*DM + h*DHD + g*16 + la] = f2bf(o_[g][r] / s_[r]);
      }
  }
}

extern "C" void kernel_launch(void* const* d_in, const int* in_sizes, int n_in,
                              void* d_out, int out_size, void* d_ws, size_t ws_size,
                              hipStream_t stream)
{
  const float* x   = (const float*)d_in[0];
  const float* wn1 = (const float*)d_in[1];
  const float* wq  = (const float*)d_in[2];
  const float* wk  = (const float*)d_in[3];
  const float* wv  = (const float*)d_in[4];
  const float* wo  = (const float*)d_in[5];
  const float* wn2 = (const float*)d_in[6];
  const float* wg  = (const float*)d_in[7];
  const float* wu  = (const float*)d_in[8];
  const float* wd  = (const float*)d_in[9];
  float* out = (float*)d_out;

  char* p = (char*)d_ws;
  auto alloc = [&](size_t bytes) { char* r = p; p += (bytes + 255) & ~(size_t)255; return r; };
  unsigned short* wqkvT = (unsigned short*)alloc((size_t)QKVW*2048*2);
  unsigned short* woT   = (unsigned short*)alloc((size_t)2048*2048*2);
  unsigned short* wguT  = (unsigned short*)alloc((size_t)2*FFP*2048*2);   // interleaved gate/up
  unsigned short* wdT   = (unsigned short*)alloc((size_t)2048*FFP*2);
  unsigned short* hb    = (unsigned short*)alloc((size_t)NTOK*2048*2);
  unsigned short* pr    = (unsigned short*)alloc((size_t)NTOK*FFP*2);
  unsigned short* qkv   = (unsigned short*)alloc((size_t)NTOK*QKVW*2);
  unsigned short* vbT   = (unsigned short*)alloc((size_t)BATCH*NKV*128*SEQ*2);
  unsigned short* ao    = (unsigned short*)alloc((size_t)NTOK*2048*2);
  float* ctab = (float*)alloc((size_t)SEQ*64*4);
  float* stab = (float*)alloc((size_t)SEQ*64*4);

  dim3 blk(256);
  k_transpose<<<dim3(2048/32, 2048/32), blk, 0, stream>>>(wq, wqkvT, 2048, 2048, 2048);
  k_transpose<<<dim3(512/32,  2048/32), blk, 0, stream>>>(wk, wqkvT + (size_t)2048*2048, 2048, 512, 2048);
  k_transpose<<<dim3(512/32,  2048/32), blk, 0, stream>>>(wv, wqkvT + (size_t)2560*2048, 2048, 512, 2048);
  k_transpose<<<dim3(2048/32, 2048/32), blk, 0, stream>>>(wo, woT, 2048, 2048, 2048);
  k_transpose_fu<<<dim3(FFP/32, 2048/32), blk, 0, stream>>>(wg, wguT, 2048, FFR, 2048, 0);
  k_transpose_fu<<<dim3(FFP/32, 2048/32), blk, 0, stream>>>(wu, wguT, 2048, FFR, 2048, 1);
  k_transpose<<<dim3(2048/32, FFP/32),  blk, 0, stream>>>(wd, wdT, FFR, 2048, FFP);

  k_rope_table<<<dim3(SEQ*64/256), blk, 0, stream>>>(ctab, stab);
  k_rmsnorm<<<dim3(NTOK), blk, 0, stream>>>(x, wn1, hb);

  k_gemm<0><<<dim3(32, QKVW/128), blk, 0, stream>>>(hb, wqkvT, qkv, nullptr, 2048, 4, QKVW);

  // K-RoPE in memory (small); Q-RoPE is fused into k_attn's register load
  k_rope_apply<<<dim3(NTOK*NKV*64/256), blk, 0, stream>>>(qkv, ctab, stab, NKV, QKVW, 2048);

  k_transpose_v<<<dim3(SEQ/32, 128/32, BATCH*NKV), blk, 0, stream>>>(qkv, vbT);

  k_attn<<<dim3(16, NH, BATCH), blk, 0, stream>>>(qkv, vbT, ao, ctab, stab);

  k_gemm<1><<<dim3(32, 16), blk, 0, stream>>>(ao, woT, (void*)out, x, 2048, 4, 2048);
  k_rmsnorm<<<dim3(NTOK), blk, 0, stream>>>(out, wn2, hb);
  // fused gate+up: B has 2*FFP rows (86 tiles x 128), output FFP cols of silu(g)*u
  k_gemm<3><<<dim3(32, 2*FFP/128), blk, 0, stream>>>(hb, wguT, pr, nullptr, 2048, 4, FFP);
  // down-proj K=5504: sw=2 keeps B-chunk (2.8 MB) L2-resident
  k_gemm<1><<<dim3(32, 16), blk, 0, stream>>>(pr, wdT, (void*)out, out, FFP, 2, 2048);
}